// Round 22
// baseline (244.406 us; speedup 1.0000x reference)
//
#include <hip/hip_runtime.h>

#define N_PTS 20000
#define KNN   16
#define DIMF  256
#define AD    128
#define MD    2500
#define EPSV  1e-5f
#define INV_SCALE 0.08838834764831845f
#define LOG2E 1.4426950408889634f
#define NEG_BIG -3.402823466e38f
#define PERSIST 2048   // blocks per branch; grid = 2*PERSIST

typedef __attribute__((ext_vector_type(8))) short short8v;
typedef __attribute__((ext_vector_type(4))) float f32x4;

__device__ __forceinline__ float b2f(unsigned short u) {
  union { unsigned int i; float f; } v; v.i = ((unsigned int)u) << 16; return v.f;
}
__device__ __forceinline__ unsigned short f2b(float f) {
  union { float f; unsigned int i; } v; v.f = f;
  unsigned int x = v.i;
  return (unsigned short)((x + 0x7fffu + ((x >> 16) & 1u)) >> 16);  // RNE
}

// canary: proj overwrites if pipeline runs
__global__ void EventAttention_54382875902362_kernel(float* out) {
  if (threadIdx.x == 0 && blockIdx.x == 0) out[0] = 8192.0f;
}

// ---------------- merged prep: w2B (attn) + hi/lo frags (qkv, proj) ---------
__global__ void prep_all(const float* __restrict__ w2l, const float* __restrict__ w2g,
                         const float* __restrict__ qwl, const float* __restrict__ qwg,
                         const float* __restrict__ pw1, const float* __restrict__ pw2,
                         unsigned short* __restrict__ w2B,
                         unsigned short* __restrict__ wfL, unsigned short* __restrict__ wfG,
                         unsigned short* __restrict__ wp1, unsigned short* __restrict__ wp2)
{
  int id = blockIdx.x * 256 + threadIdx.x;
  if (id < 32768) {
    int br  = id >> 14;
    int rem = id & 16383;
    int e  = rem & 7;
    int l  = (rem >> 3) & 63;
    int ks = (rem >> 9) & 3;
    int tt = rem >> 11;
    int n = tt * 16 + (l & 15);
    int i = ks * 32 + (l >> 4) * 8 + e;
    const float* src = br ? w2g : w2l;
    w2B[id] = f2b(src[i * AD + n]);
    return;
  }
  id -= 32768;
  const float* src;
  unsigned short* dst;
  int ncols, fe;
  if (id < 98304)            { src = qwl; dst = wfL; ncols = 384; fe = 98304; }
  else if (id < 196608)      { src = qwg; dst = wfG; ncols = 384; fe = 98304; id -= 98304; }
  else if (id < 262144)      { src = pw1; dst = wp1; ncols = 256; fe = 65536; id -= 196608; }
  else if (id < 327680)      { src = pw2; dst = wp2; ncols = 256; fe = 65536; id -= 262144; }
  else return;
  int e  = id & 7;
  int l  = (id >> 3) & 63;
  int ks = (id >> 9) & 7;
  int tt = id >> 12;
  int n = tt * 16 + (l & 15);
  int k = ks * 32 + (l >> 4) * 8 + e;
  float v = src[k * ncols + n];
  unsigned short hi = f2b(v);
  unsigned short lo = f2b(v - b2f(hi));
  dst[id] = hi;
  dst[fe + id] = lo;
}

// ---------------- QKV GEMM via MFMA hi/lo: grid 2500 x 256 ------------------
__global__ void qkv_mfma(const float* __restrict__ feat,
                         const unsigned short* __restrict__ wfl, const float* __restrict__ bl,
                         const unsigned short* __restrict__ wfg, const float* __restrict__ bg,
                         float* __restrict__ qkv_l, float* __restrict__ qkv_g,
                         unsigned short* __restrict__ kvl)
{
  __shared__ __align__(16) unsigned short aHi[16 * 256];
  __shared__ __align__(16) unsigned short aLo[16 * 256];
  const int tid  = threadIdx.x;
  const int lane = tid & 63;
  const int wv   = tid >> 6;
  const int br   = blockIdx.x & 1;
  const int row0 = (blockIdx.x >> 1) * 16;

  {
    int r = tid >> 4, seg = tid & 15;
    const float4* src = (const float4*)(feat + (size_t)(row0 + r) * 256 + seg * 16);
    #pragma unroll
    for (int q4 = 0; q4 < 4; ++q4) {
      float4 f = src[q4];
      int byte = (r * 512 + (seg * 16 + q4 * 4) * 2) ^ ((r & 7) << 4);
      ushort4 h, l2;
      h.x = f2b(f.x); l2.x = f2b(f.x - b2f(h.x));
      h.y = f2b(f.y); l2.y = f2b(f.y - b2f(h.y));
      h.z = f2b(f.z); l2.z = f2b(f.z - b2f(h.z));
      h.w = f2b(f.w); l2.w = f2b(f.w - b2f(h.w));
      *(ushort4*)((char*)aHi + byte) = h;
      *(ushort4*)((char*)aLo + byte) = l2;
    }
  }
  __syncthreads();

  short8v ah[8], al[8];
  #pragma unroll
  for (int ks = 0; ks < 8; ++ks) {
    int base = ((lane & 15) * 512 + ks * 64 + (lane >> 4) * 16) ^ ((lane & 7) << 4);
    ah[ks] = *(const short8v*)((const char*)aHi + base);
    al[ks] = *(const short8v*)((const char*)aLo + base);
  }
  const unsigned short* wf = br ? wfg : wfl;
  const float* bias        = br ? bg : bl;
  const short8v* wH = (const short8v*)wf;
  const short8v* wL = wH + 12288;
  f32x4 acc[6];
  #pragma unroll
  for (int t = 0; t < 6; ++t) acc[t] = (f32x4){0.f, 0.f, 0.f, 0.f};
  #pragma unroll
  for (int t = 0; t < 6; ++t) {
    int tt = wv * 6 + t;
    #pragma unroll
    for (int ks = 0; ks < 8; ++ks) {
      short8v bh = wH[(tt * 8 + ks) * 64 + lane];
      short8v bo = wL[(tt * 8 + ks) * 64 + lane];
      acc[t] = __builtin_amdgcn_mfma_f32_16x16x32_bf16(ah[ks], bh, acc[t], 0, 0, 0);
      acc[t] = __builtin_amdgcn_mfma_f32_16x16x32_bf16(al[ks], bh, acc[t], 0, 0, 0);
      acc[t] = __builtin_amdgcn_mfma_f32_16x16x32_bf16(ah[ks], bo, acc[t], 0, 0, 0);
    }
  }
  if (br) {
    #pragma unroll
    for (int t = 0; t < 6; ++t) {
      int colb = (wv * 6 + t) * 16 + (lane & 15);
      float bv = bias[colb];
      #pragma unroll
      for (int r = 0; r < 4; ++r) {
        int row = (lane >> 4) * 4 + r;
        qkv_g[(size_t)(row0 + row) * 384 + colb] = acc[t][r] + bv;
      }
    }
  } else {
    #pragma unroll
    for (int t = 0; t < 6; ++t) {
      int colb = (wv * 6 + t) * 16 + (lane & 15);
      float bv = bias[colb];
      #pragma unroll
      for (int r = 0; r < 4; ++r) {
        int row = (lane >> 4) * 4 + r;
        float val = acc[t][r] + bv;
        if (colb < 128) {
          qkv_l[(size_t)(row0 + row) * 384 + colb] = val;      // q (f32)
        } else if (colb < 256) {
          kvl[(size_t)(row0 + row) * 256 + 2 * (colb - 128)] = f2b(val);      // k
        } else {
          kvl[(size_t)(row0 + row) * 256 + 2 * (colb - 256) + 1] = f2b(val);  // v
        }
      }
    }
  }
}

// ---------------- kmax/vmax pooling -> packed bf16: grid MD x 128 -----------
__global__ void kvmax_kernel(const float* __restrict__ qkv_g,
                             const int* __restrict__ pair_idx,
                             unsigned int* __restrict__ kvm)
{
  const int m = blockIdx.x, a = threadIdx.x;
  float km = NEG_BIG, vm = NEG_BIG;
  for (int j = 0; j < KNN; ++j) {
    int p = pair_idx[m * KNN + j];
    km = fmaxf(km, qkv_g[(size_t)p * 384 + 128 + a]);
    vm = fmaxf(vm, qkv_g[(size_t)p * 384 + 256 + a]);
  }
  kvm[m * AD + a] = (unsigned int)f2b(km) | ((unsigned int)f2b(vm) << 16);
}

// ---------------- fused attention, PERSISTENT blocks ------------------------
// grid 2*PERSIST x 128. bid&1 = branch; each block strides over n. Weight
// prologue (8 loads) hoisted out of the loop; 40000 block launches -> 4096.
__global__ __launch_bounds__(128)
void attn_fused(const float* __restrict__ events,
                const int* __restrict__ local_idx,
                const int* __restrict__ inv_pair_idx,
                const int* __restrict__ down_idx,
                const float* __restrict__ qkv_l,
                const float* __restrict__ qkv_g,
                const unsigned int* __restrict__ kvl,
                const unsigned int* __restrict__ kvm,
                const float* __restrict__ w1L, const float* __restrict__ b1L,
                const unsigned short* __restrict__ w2BL, const float* __restrict__ b2L,
                const float* __restrict__ gL,  const float* __restrict__ bbL,
                const float* __restrict__ w1G, const float* __restrict__ b1G,
                const unsigned short* __restrict__ w2BG, const float* __restrict__ b2G,
                const float* __restrict__ gG,  const float* __restrict__ bbG,
                float* __restrict__ out)
{
  __shared__ __align__(16) float uS[KNN * 132];  // low 4KB doubles as hB
  __shared__ float dS[KNN][4];
  __shared__ int   idxS[KNN];
  __shared__ __align__(16) float red[KNN][4];
  __shared__ __align__(8)  float statS[KNN][2];

  unsigned short* hB = (unsigned short*)uS;
  float* scratch = uS;

  const int bid  = blockIdx.x;
  const int gbr  = bid & 1;               // 0 = local, 1 = global
  const int a    = threadIdx.x;
  const int lane = a & 63;
  const int wv   = a >> 6;

  const int*          idx = gbr ? inv_pair_idx : local_idx;
  const float*        qt  = gbr ? qkv_g : qkv_l;
  const unsigned int* kvt = gbr ? kvm : kvl;
  const float* w1  = gbr ? w1G : w1L;
  const float* b1  = gbr ? b1G : b1L;
  const unsigned short* w2B = gbr ? w2BG : w2BL;
  const float* b2  = gbr ? b2G : b2L;
  const float* gg  = gbr ? gG : gL;
  const float* bbp = gbr ? bbG : bbL;
  const short8v* wf = (const short8v*)w2B;

  // loop-invariant prologue (was paid per block x 40000)
  const float w1r0 = w1[0 * AD + a];
  const float w1r1 = w1[1 * AD + a];
  const float w1r2 = w1[2 * AD + a];
  const float w1r3 = w1[3 * AD + a];
  const float b1r = b1[a];
  const float b2r = b2[a];
  const float gr  = gg[a] * (INV_SCALE * LOG2E);
  const float brv = bbp[a] * (INV_SCALE * LOG2E);

  for (int n = bid >> 1; n < N_PTS; n += PERSIST) {
    // stage neighbor indices + coord diffs (64 threads)
    if (a < KNN * 4) {
      int j = a >> 2, c = a & 3;
      int idv = idx[n * KNN + j];
      if (c == 0) idxS[j] = idv;
      int erow = gbr ? down_idx[idv] : idv;
      dS[j][c] = events[(size_t)n * 4 + c] - events[(size_t)erow * 4 + c];
    }
    const float qv = qt[(size_t)n * 384 + a];
    __syncthreads();

    // layer 1 -> bf16 swizzled hB
    #pragma unroll
    for (int j = 0; j < KNN; ++j) {
      const float4 d = *(const float4*)dS[j];
      float h = b1r;
      h = fmaf(d.x, w1r0, h);
      h = fmaf(d.y, w1r1, h);
      h = fmaf(d.z, w1r2, h);
      h = fmaf(d.w, w1r3, h);
      h = fmaxf(h, 0.f);
      int byte = (j * 256 + a * 2) ^ ((j & 7) << 4);
      *(unsigned short*)((char*)hB + byte) = f2b(h);
    }
    __syncthreads();

    // A-frags from hB (last use of the hB alias)
    short8v af[4];
    #pragma unroll
    for (int ksl = 0; ksl < 4; ++ksl) {
      int base = ((lane & 15) * 256 + ksl * 64 + (lane >> 4) * 16) ^ ((lane & 7) << 4);
      af[ksl] = *(const short8v*)((const char*)hB + base);
    }
    __syncthreads();  // union hazard: hB reads done before scratch overwrite

    // MFMA pe_raw = h @ w2
    f32x4 acc[4];
    #pragma unroll
    for (int t = 0; t < 4; ++t) acc[t] = (f32x4){0.f, 0.f, 0.f, 0.f};
    #pragma unroll
    for (int t = 0; t < 4; ++t) {
      #pragma unroll
      for (int ksl = 0; ksl < 4; ++ksl) {
        short8v bf = wf[(((wv * 4 + t) * 4 + ksl) * 64) + lane];
        acc[t] = __builtin_amdgcn_mfma_f32_16x16x32_bf16(af[ksl], bf, acc[t], 0, 0, 0);
      }
    }
    #pragma unroll
    for (int t = 0; t < 4; ++t) {
      #pragma unroll
      for (int r = 0; r < 4; ++r) {
        int row = (lane >> 4) * 4 + r;
        int col = wv * 64 + t * 16 + (lane & 15);
        scratch[row * 132 + col] = acc[t][r];
      }
    }
    __syncthreads();

    // pe-phase: one packed-kv dword per j, fold pe immediately
    float x[KNN], w[KNN];
    #pragma unroll
    for (int j = 0; j < KNN; ++j) {
      int sid = __builtin_amdgcn_readfirstlane(idxS[j]);
      unsigned int kv = kvt[(size_t)sid * AD + a];
      float pe = scratch[j * 132 + a] + b2r;
      x[j] = qv - b2f((unsigned short)kv) + pe;
      w[j] = b2f((unsigned short)(kv >> 16)) + pe;
    }
    __syncthreads();

    #pragma unroll
    for (int j = 0; j < KNN; ++j) scratch[j * 132 + a] = x[j];
    __syncthreads();

    // LN partial sums
    {
      int jj = a & 15, pp = a >> 4;
      const float4* rowp = (const float4*)&scratch[jj * 132 + pp * 16];
      float s1 = 0.f, s2 = 0.f;
      #pragma unroll
      for (int q = 0; q < 4; ++q) {
        float4 v4 = rowp[q];
        s1 += v4.x + v4.y + v4.z + v4.w;
        s2 = fmaf(v4.x, v4.x, s2);
        s2 = fmaf(v4.y, v4.y, s2);
        s2 = fmaf(v4.z, v4.z, s2);
        s2 = fmaf(v4.w, v4.w, s2);
      }
      s1 += __shfl_xor(s1, 16, 64); s2 += __shfl_xor(s2, 16, 64);
      s1 += __shfl_xor(s1, 32, 64); s2 += __shfl_xor(s2, 32, 64);
      if (lane < 16) { red[jj][wv * 2] = s1; red[jj][wv * 2 + 1] = s2; }
    }
    __syncthreads();

    if (a < KNN) {
      const float4 rr = *(const float4*)red[a];
      float S1 = rr.x + rr.z;
      float S2 = rr.y + rr.w;
      float mu  = S1 * (1.f / AD);
      float var = fmaf(S2, 1.f / AD, -mu * mu);
      statS[a][0] = mu;
      statS[a][1] = rsqrtf(var + EPSV);
    }
    __syncthreads();

    // LN apply + softmax (no max pass; exp2-safe) + output
    float sum = 0.f;
    #pragma unroll
    for (int j = 0; j < KNN; ++j) {
      const float2 st = *(const float2*)statS[j];
      float s = fmaf((x[j] - st.x) * st.y, gr, brv);
      float p = exp2f(s);
      x[j] = p;
      sum += p;
    }
    const float inv = 1.f / sum;
    float o = 0.f;
    #pragma unroll
    for (int j = 0; j < KNN; ++j)
      o = fmaf(x[j], w[j], o);
    out[(size_t)n * 256 + (gbr ? 128 : 0) + a] = o * inv;
    __syncthreads();  // next iter's dS/idxS staging must not race this iter
  }
}

// ---------------- proj MLP via MFMA hi/lo: grid 1250 x 256 ------------------
__global__ void proj_mfma(const float* __restrict__ attn_cat,
                          const unsigned short* __restrict__ w1f, const float* __restrict__ b1,
                          const unsigned short* __restrict__ w2f, const float* __restrict__ b2,
                          float* __restrict__ outp)
{
  __shared__ __align__(16) unsigned short aHi[16 * 256];
  __shared__ __align__(16) unsigned short aLo[16 * 256];
  const int tid  = threadIdx.x;
  const int lane = tid & 63;
  const int wv   = tid >> 6;
  const int row0 = blockIdx.x * 16;

  {
    int r = tid >> 4, seg = tid & 15;
    const float4* src = (const float4*)(attn_cat + (size_t)(row0 + r) * 256 + seg * 16);
    #pragma unroll
    for (int q4 = 0; q4 < 4; ++q4) {
      float4 f = src[q4];
      int byte = (r * 512 + (seg * 16 + q4 * 4) * 2) ^ ((r & 7) << 4);
      ushort4 h, l2;
      h.x = f2b(f.x); l2.x = f2b(f.x - b2f(h.x));
      h.y = f2b(f.y); l2.y = f2b(f.y - b2f(h.y));
      h.z = f2b(f.z); l2.z = f2b(f.z - b2f(h.z));
      h.w = f2b(f.w); l2.w = f2b(f.w - b2f(h.w));
      *(ushort4*)((char*)aHi + byte) = h;
      *(ushort4*)((char*)aLo + byte) = l2;
    }
  }
  __syncthreads();

  short8v ah[8], al[8];
  #pragma unroll
  for (int ks = 0; ks < 8; ++ks) {
    int base = ((lane & 15) * 512 + ks * 64 + (lane >> 4) * 16) ^ ((lane & 7) << 4);
    ah[ks] = *(const short8v*)((const char*)aHi + base);
    al[ks] = *(const short8v*)((const char*)aLo + base);
  }
  __syncthreads();

  const short8v* w1H = (const short8v*)w1f;
  const short8v* w1L = w1H + 8192;
  f32x4 acc[4];
  #pragma unroll
  for (int t = 0; t < 4; ++t) acc[t] = (f32x4){0.f, 0.f, 0.f, 0.f};
  #pragma unroll
  for (int t = 0; t < 4; ++t) {
    int tt = wv * 4 + t;
    #pragma unroll
    for (int ks = 0; ks < 8; ++ks) {
      short8v bh = w1H[(tt * 8 + ks) * 64 + lane];
      short8v bo = w1L[(tt * 8 + ks) * 64 + lane];
      acc[t] = __builtin_amdgcn_mfma_f32_16x16x32_bf16(ah[ks], bh, acc[t], 0, 0, 0);
      acc[t] = __builtin_amdgcn_mfma_f32_16x16x32_bf16(al[ks], bh, acc[t], 0, 0, 0);
      acc[t] = __builtin_amdgcn_mfma_f32_16x16x32_bf16(ah[ks], bo, acc[t], 0, 0, 0);
    }
  }
  #pragma unroll
  for (int t = 0; t < 4; ++t) {
    int col = (wv * 4 + t) * 16 + (lane & 15);
    float bvv = b1[col];
    #pragma unroll
    for (int r = 0; r < 4; ++r) {
      int row = (lane >> 4) * 4 + r;
      float h = fmaxf(acc[t][r] + bvv, 0.f);
      unsigned short hi = f2b(h);
      unsigned short lo = f2b(h - b2f(hi));
      int byte = (row * 512 + col * 2) ^ ((row & 7) << 4);
      *(unsigned short*)((char*)aHi + byte) = hi;
      *(unsigned short*)((char*)aLo + byte) = lo;
    }
  }
  __syncthreads();

  #pragma unroll
  for (int ks = 0; ks < 8; ++ks) {
    int base = ((lane & 15) * 512 + ks * 64 + (lane >> 4) * 16) ^ ((lane & 7) << 4);
    ah[ks] = *(const short8v*)((const char*)aHi + base);
    al[ks] = *(const short8v*)((const char*)aLo + base);
  }
  const short8v* w2H = (const short8v*)w2f;
  const short8v* w2L = w2H + 8192;
  #pragma unroll
  for (int t = 0; t < 4; ++t) acc[t] = (f32x4){0.f, 0.f, 0.f, 0.f};
  #pragma unroll
  for (int t = 0; t < 4; ++t) {
    int tt = wv * 4 + t;
    #pragma unroll
    for (int ks = 0; ks < 8; ++ks) {
      short8v bh = w2H[(tt * 8 + ks) * 64 + lane];
      short8v bo = w2L[(tt * 8 + ks) * 64 + lane];
      acc[t] = __builtin_amdgcn_mfma_f32_16x16x32_bf16(ah[ks], bh, acc[t], 0, 0, 0);
      acc[t] = __builtin_amdgcn_mfma_f32_16x16x32_bf16(al[ks], bh, acc[t], 0, 0, 0);
      acc[t] = __builtin_amdgcn_mfma_f32_16x16x32_bf16(ah[ks], bo, acc[t], 0, 0, 0);
    }
  }
  #pragma unroll
  for (int t = 0; t < 4; ++t) {
    int col = (wv * 4 + t) * 16 + (lane & 15);
    float bvv = b2[col];
    #pragma unroll
    for (int r = 0; r < 4; ++r) {
      int row = (lane >> 4) * 4 + r;
      outp[(size_t)(row0 + row) * 256 + col] = acc[t][r] + bvv;
    }
  }
}

// ---------------- launch ----------------------------------------------------
extern "C" void kernel_launch(void* const* d_in, const int* in_sizes, int n_in,
                              void* d_out, int out_size, void* d_ws, size_t ws_size,
                              hipStream_t stream)
{
  const float* events   = (const float*)d_in[0];
  const float* features = (const float*)d_in[1];
  const int* local_idx    = (const int*)d_in[2];
  const int* down_idx     = (const int*)d_in[3];
  const int* pair_idx     = (const int*)d_in[4];
  const int* inv_pair_idx = (const int*)d_in[5];
  const float* l_qkv_w = (const float*)d_in[6];
  const float* l_qkv_b = (const float*)d_in[7];
  const float* l_pe_w1 = (const float*)d_in[8];
  const float* l_pe_b1 = (const float*)d_in[9];
  const float* l_pe_w2 = (const float*)d_in[10];
  const float* l_pe_b2 = (const float*)d_in[11];
  const float* l_fc_g  = (const float*)d_in[12];
  const float* l_fc_b  = (const float*)d_in[13];
  const float* g_qkv_w = (const float*)d_in[14];
  const float* g_qkv_b = (const float*)d_in[15];
  const float* g_pe_w1 = (const float*)d_in[16];
  const float* g_pe_b1 = (const float*)d_in[17];
  const float* g_pe_w2 = (const float*)d_in[18];
  const float* g_pe_b2 = (const float*)d_in[19];
  const float* g_fc_g  = (const float*)d_in[20];
  const float* g_fc_b  = (const float*)d_in[21];
  const float* p_w1 = (const float*)d_in[22];
  const float* p_b1 = (const float*)d_in[23];
  const float* p_w2 = (const float*)d_in[24];
  const float* p_b2 = (const float*)d_in[25];
  (void)in_sizes; (void)n_in; (void)out_size; (void)ws_size;

  char* ws = (char*)d_ws;
  size_t off = 0;
  float* qkv_l    = (float*)(ws + off); off += (size_t)N_PTS * 384 * 4;
  float* qkv_g    = (float*)(ws + off); off += (size_t)N_PTS * 384 * 4;
  unsigned short* kvl = (unsigned short*)(ws + off); off += (size_t)N_PTS * 256 * 2;
  unsigned int*   kvm = (unsigned int*)(ws + off);   off += (size_t)MD * AD * 4;
  float* attn_cat = (float*)(ws + off); off += (size_t)N_PTS * 256 * 4;
  unsigned short* w2B   = (unsigned short*)(ws + off); off += 32768 * 2;
  unsigned short* wfL   = (unsigned short*)(ws + off); off += 196608 * 2;
  unsigned short* wfG   = (unsigned short*)(ws + off); off += 196608 * 2;
  unsigned short* wp1   = (unsigned short*)(ws + off); off += 131072 * 2;
  unsigned short* wp2   = (unsigned short*)(ws + off); off += 131072 * 2;

  EventAttention_54382875902362_kernel<<<1, 64, 0, stream>>>((float*)d_out);
  prep_all<<<1408, 256, 0, stream>>>(
      l_pe_w2, g_pe_w2, l_qkv_w, g_qkv_w, p_w1, p_w2,
      w2B, wfL, wfG, wp1, wp2);

  qkv_mfma<<<2500, 256, 0, stream>>>(
      features, wfL, l_qkv_b, wfG, g_qkv_b, qkv_l, qkv_g, kvl);
  kvmax_kernel<<<MD, 128, 0, stream>>>(qkv_g, pair_idx, kvm);
  attn_fused<<<2 * PERSIST, 128, 0, stream>>>(
      events, local_idx, inv_pair_idx, down_idx,
      qkv_l, qkv_g, (const unsigned int*)kvl, kvm,
      l_pe_w1, l_pe_b1, w2B, l_pe_b2, l_fc_g, l_fc_b,
      g_pe_w1, g_pe_b1, w2B + 16384, g_pe_b2, g_fc_g, g_fc_b,
      attn_cat);
  proj_mfma<<<N_PTS / 16, 256, 0, stream>>>(
      attn_cat, wp1, p_b1, wp2, p_b2, (float*)d_out);
}

// Round 23
// 196.224 us; speedup vs baseline: 1.2455x; 1.2455x over previous
//
#include <hip/hip_runtime.h>

#define N_PTS 20000
#define KNN   16
#define DIMF  256
#define AD    128
#define MD    2500
#define EPSV  1e-5f
#define INV_SCALE 0.08838834764831845f
#define LOG2E 1.4426950408889634f
#define NEG_BIG -3.402823466e38f

typedef __attribute__((ext_vector_type(8))) short short8v;
typedef __attribute__((ext_vector_type(4))) float f32x4;

__device__ __forceinline__ float b2f(unsigned short u) {
  union { unsigned int i; float f; } v; v.i = ((unsigned int)u) << 16; return v.f;
}
__device__ __forceinline__ unsigned short f2b(float f) {
  union { float f; unsigned int i; } v; v.f = f;
  unsigned int x = v.i;
  return (unsigned short)((x + 0x7fffu + ((x >> 16) & 1u)) >> 16);  // RNE
}

// canary: proj overwrites if pipeline runs
__global__ void EventAttention_54382875902362_kernel(float* out) {
  if (threadIdx.x == 0 && blockIdx.x == 0) out[0] = 8192.0f;
}

// ---------------- merged prep: w2B (attn) + hi/lo frags (qkv, proj) ---------
__global__ void prep_all(const float* __restrict__ w2l, const float* __restrict__ w2g,
                         const float* __restrict__ qwl, const float* __restrict__ qwg,
                         const float* __restrict__ pw1, const float* __restrict__ pw2,
                         unsigned short* __restrict__ w2B,
                         unsigned short* __restrict__ wfL, unsigned short* __restrict__ wfG,
                         unsigned short* __restrict__ wp1, unsigned short* __restrict__ wp2)
{
  int id = blockIdx.x * 256 + threadIdx.x;
  if (id < 32768) {
    int br  = id >> 14;
    int rem = id & 16383;
    int e  = rem & 7;
    int l  = (rem >> 3) & 63;
    int ks = (rem >> 9) & 3;
    int tt = rem >> 11;
    int n = tt * 16 + (l & 15);
    int i = ks * 32 + (l >> 4) * 8 + e;
    const float* src = br ? w2g : w2l;
    w2B[id] = f2b(src[i * AD + n]);
    return;
  }
  id -= 32768;
  const float* src;
  unsigned short* dst;
  int ncols, fe;
  if (id < 98304)            { src = qwl; dst = wfL; ncols = 384; fe = 98304; }
  else if (id < 196608)      { src = qwg; dst = wfG; ncols = 384; fe = 98304; id -= 98304; }
  else if (id < 262144)      { src = pw1; dst = wp1; ncols = 256; fe = 65536; id -= 196608; }
  else if (id < 327680)      { src = pw2; dst = wp2; ncols = 256; fe = 65536; id -= 262144; }
  else return;
  int e  = id & 7;
  int l  = (id >> 3) & 63;
  int ks = (id >> 9) & 7;
  int tt = id >> 12;
  int n = tt * 16 + (l & 15);
  int k = ks * 32 + (l >> 4) * 8 + e;
  float v = src[k * ncols + n];
  unsigned short hi = f2b(v);
  unsigned short lo = f2b(v - b2f(hi));
  dst[id] = hi;
  dst[fe + id] = lo;
}

// ---------------- QKV GEMM via MFMA hi/lo: grid 2500 x 256 ------------------
// bid&1 = branch, bid>>1 = 16-row tile. (r19 lesson: do NOT fuse branches.)
__global__ void qkv_mfma(const float* __restrict__ feat,
                         const unsigned short* __restrict__ wfl, const float* __restrict__ bl,
                         const unsigned short* __restrict__ wfg, const float* __restrict__ bg,
                         float* __restrict__ qkv_l, float* __restrict__ qkv_g,
                         unsigned short* __restrict__ kvl)
{
  __shared__ __align__(16) unsigned short aHi[16 * 256];
  __shared__ __align__(16) unsigned short aLo[16 * 256];
  const int tid  = threadIdx.x;
  const int lane = tid & 63;
  const int wv   = tid >> 6;
  const int br   = blockIdx.x & 1;
  const int row0 = (blockIdx.x >> 1) * 16;

  {
    int r = tid >> 4, seg = tid & 15;
    const float4* src = (const float4*)(feat + (size_t)(row0 + r) * 256 + seg * 16);
    #pragma unroll
    for (int q4 = 0; q4 < 4; ++q4) {
      float4 f = src[q4];
      int byte = (r * 512 + (seg * 16 + q4 * 4) * 2) ^ ((r & 7) << 4);
      ushort4 h, l2;
      h.x = f2b(f.x); l2.x = f2b(f.x - b2f(h.x));
      h.y = f2b(f.y); l2.y = f2b(f.y - b2f(h.y));
      h.z = f2b(f.z); l2.z = f2b(f.z - b2f(h.z));
      h.w = f2b(f.w); l2.w = f2b(f.w - b2f(h.w));
      *(ushort4*)((char*)aHi + byte) = h;
      *(ushort4*)((char*)aLo + byte) = l2;
    }
  }
  __syncthreads();

  short8v ah[8], al[8];
  #pragma unroll
  for (int ks = 0; ks < 8; ++ks) {
    int base = ((lane & 15) * 512 + ks * 64 + (lane >> 4) * 16) ^ ((lane & 7) << 4);
    ah[ks] = *(const short8v*)((const char*)aHi + base);
    al[ks] = *(const short8v*)((const char*)aLo + base);
  }
  const unsigned short* wf = br ? wfg : wfl;
  const float* bias        = br ? bg : bl;
  const short8v* wH = (const short8v*)wf;
  const short8v* wL = wH + 12288;
  f32x4 acc[6];
  #pragma unroll
  for (int t = 0; t < 6; ++t) acc[t] = (f32x4){0.f, 0.f, 0.f, 0.f};
  #pragma unroll
  for (int t = 0; t < 6; ++t) {
    int tt = wv * 6 + t;
    #pragma unroll
    for (int ks = 0; ks < 8; ++ks) {
      short8v bh = wH[(tt * 8 + ks) * 64 + lane];
      short8v bo = wL[(tt * 8 + ks) * 64 + lane];
      acc[t] = __builtin_amdgcn_mfma_f32_16x16x32_bf16(ah[ks], bh, acc[t], 0, 0, 0);
      acc[t] = __builtin_amdgcn_mfma_f32_16x16x32_bf16(al[ks], bh, acc[t], 0, 0, 0);
      acc[t] = __builtin_amdgcn_mfma_f32_16x16x32_bf16(ah[ks], bo, acc[t], 0, 0, 0);
    }
  }
  if (br) {
    #pragma unroll
    for (int t = 0; t < 6; ++t) {
      int colb = (wv * 6 + t) * 16 + (lane & 15);
      float bv = bias[colb];
      #pragma unroll
      for (int r = 0; r < 4; ++r) {
        int row = (lane >> 4) * 4 + r;
        qkv_g[(size_t)(row0 + row) * 384 + colb] = acc[t][r] + bv;
      }
    }
  } else {
    #pragma unroll
    for (int t = 0; t < 6; ++t) {
      int colb = (wv * 6 + t) * 16 + (lane & 15);
      float bv = bias[colb];
      #pragma unroll
      for (int r = 0; r < 4; ++r) {
        int row = (lane >> 4) * 4 + r;
        float val = acc[t][r] + bv;
        if (colb < 128) {
          qkv_l[(size_t)(row0 + row) * 384 + colb] = val;      // q (f32)
        } else if (colb < 256) {
          kvl[(size_t)(row0 + row) * 256 + 2 * (colb - 128)] = f2b(val);      // k
        } else {
          kvl[(size_t)(row0 + row) * 256 + 2 * (colb - 256) + 1] = f2b(val);  // v
        }
      }
    }
  }
}

// ---------------- kmax/vmax pooling -> packed bf16: grid MD x 128 -----------
__global__ void kvmax_kernel(const float* __restrict__ qkv_g,
                             const int* __restrict__ pair_idx,
                             unsigned int* __restrict__ kvm)
{
  const int m = blockIdx.x, a = threadIdx.x;
  float km = NEG_BIG, vm = NEG_BIG;
  for (int j = 0; j < KNN; ++j) {
    int p = pair_idx[m * KNN + j];
    km = fmaxf(km, qkv_g[(size_t)p * 384 + 128 + a]);
    vm = fmaxf(vm, qkv_g[(size_t)p * 384 + 256 + a]);
  }
  kvm[m * AD + a] = (unsigned int)f2b(km) | ((unsigned int)f2b(vm) << 16);
}

// ---------------- fused attention (round-20 verified best) ------------------
// grid 2*N x 128. blockIdx&1 = branch.
__global__ __launch_bounds__(128)
void attn_fused(const float* __restrict__ events,
                const int* __restrict__ local_idx,
                const int* __restrict__ inv_pair_idx,
                const int* __restrict__ down_idx,
                const float* __restrict__ qkv_l,
                const float* __restrict__ qkv_g,
                const unsigned int* __restrict__ kvl,
                const unsigned int* __restrict__ kvm,
                const float* __restrict__ w1L, const float* __restrict__ b1L,
                const unsigned short* __restrict__ w2BL, const float* __restrict__ b2L,
                const float* __restrict__ gL,  const float* __restrict__ bbL,
                const float* __restrict__ w1G, const float* __restrict__ b1G,
                const unsigned short* __restrict__ w2BG, const float* __restrict__ b2G,
                const float* __restrict__ gG,  const float* __restrict__ bbG,
                float* __restrict__ out)
{
  __shared__ __align__(16) unsigned short hB[KNN * AD];
  __shared__ __align__(16) float scratch[KNN * 132];
  __shared__ float dS[KNN][4];
  __shared__ int   idxS[KNN];
  __shared__ __align__(16) float red[KNN][4];   // [j][{S1w0,S2w0,S1w1,S2w1}]
  __shared__ __align__(8)  float statS[KNN][2]; // [j][{mu, rs}]

  const int bid  = blockIdx.x;
  const int gbr  = bid & 1;               // 0 = local, 1 = global
  const int n    = bid >> 1;
  const int a    = threadIdx.x;
  const int lane = a & 63;
  const int wv   = a >> 6;

  const int*          idx = gbr ? inv_pair_idx : local_idx;
  const float*        qt  = gbr ? qkv_g : qkv_l;
  const unsigned int* kvt = gbr ? kvm : kvl;   // [row][a] = (bf16 k | bf16 v<<16)
  const float* w1  = gbr ? w1G : w1L;
  const float* b1  = gbr ? b1G : b1L;
  const unsigned short* w2B = gbr ? w2BG : w2BL;
  const float* b2  = gbr ? b2G : b2L;
  const float* gg  = gbr ? gG : gL;
  const float* bbp = gbr ? bbG : bbL;

  // stage neighbor indices + coord diffs (64 threads)
  if (a < KNN * 4) {
    int j = a >> 2, c = a & 3;
    int idv = idx[n * KNN + j];
    if (c == 0) idxS[j] = idv;
    int erow = gbr ? down_idx[idv] : idv;
    dS[j][c] = events[(size_t)n * 4 + c] - events[(size_t)erow * 4 + c];
  }
  const float w1r0 = w1[0 * AD + a];
  const float w1r1 = w1[1 * AD + a];
  const float w1r2 = w1[2 * AD + a];
  const float w1r3 = w1[3 * AD + a];
  const float b1r = b1[a];
  const float b2r = b2[a];
  const float gr  = gg[a] * (INV_SCALE * LOG2E);   // exp2-domain fold
  const float brv = bbp[a] * (INV_SCALE * LOG2E);
  const float qv  = qt[(size_t)n * 384 + a];
  __syncthreads();

  // layer 1 -> bf16 swizzled hB (VALU: K=4 is below MFMA threshold, r17)
  #pragma unroll
  for (int j = 0; j < KNN; ++j) {
    const float4 d = *(const float4*)dS[j];
    float h = b1r;
    h = fmaf(d.x, w1r0, h);
    h = fmaf(d.y, w1r1, h);
    h = fmaf(d.z, w1r2, h);
    h = fmaf(d.w, w1r3, h);
    h = fmaxf(h, 0.f);
    int byte = (j * 256 + a * 2) ^ ((j & 7) << 4);
    *(unsigned short*)((char*)hB + byte) = f2b(h);
  }
  __syncthreads();

  // MFMA pe_raw = h @ w2 (this wave handles col-tiles wv*4..wv*4+3)
  short8v af[4];
  #pragma unroll
  for (int ksl = 0; ksl < 4; ++ksl) {
    int base = ((lane & 15) * 256 + ksl * 64 + (lane >> 4) * 16) ^ ((lane & 7) << 4);
    af[ksl] = *(const short8v*)((const char*)hB + base);
  }
  f32x4 acc[4];
  #pragma unroll
  for (int t = 0; t < 4; ++t) acc[t] = (f32x4){0.f, 0.f, 0.f, 0.f};
  const short8v* wf = (const short8v*)w2B;
  #pragma unroll
  for (int t = 0; t < 4; ++t) {
    #pragma unroll
    for (int ksl = 0; ksl < 4; ++ksl) {
      short8v bf = wf[(((wv * 4 + t) * 4 + ksl) * 64) + lane];
      acc[t] = __builtin_amdgcn_mfma_f32_16x16x32_bf16(af[ksl], bf, acc[t], 0, 0, 0);
    }
  }
  #pragma unroll
  for (int t = 0; t < 4; ++t) {
    #pragma unroll
    for (int r = 0; r < 4; ++r) {
      int row = (lane >> 4) * 4 + r;
      int col = wv * 64 + t * 16 + (lane & 15);
      scratch[row * 132 + col] = acc[t][r];
    }
  }
  __syncthreads();

  // pe-phase: one packed-kv dword per j (scalar base), fold pe immediately.
  float x[KNN], w[KNN];
  #pragma unroll
  for (int j = 0; j < KNN; ++j) {
    int sid = __builtin_amdgcn_readfirstlane(idxS[j]);   // block-uniform -> SGPR
    unsigned int kv = kvt[(size_t)sid * AD + a];
    float pe = scratch[j * 132 + a] + b2r;
    x[j] = qv - b2f((unsigned short)kv) + pe;
    w[j] = b2f((unsigned short)(kv >> 16)) + pe;
  }
  __syncthreads();  // pe reads done before scratch reuse

  #pragma unroll
  for (int j = 0; j < KNN; ++j) scratch[j * 132 + a] = x[j];
  __syncthreads();

  // LN partial sums: b128 reads (stride 132 keeps 16B alignment)
  {
    int jj = a & 15, pp = a >> 4;
    const float4* rowp = (const float4*)&scratch[jj * 132 + pp * 16];
    float s1 = 0.f, s2 = 0.f;
    #pragma unroll
    for (int q = 0; q < 4; ++q) {
      float4 v4 = rowp[q];
      s1 += v4.x + v4.y + v4.z + v4.w;
      s2 = fmaf(v4.x, v4.x, s2);
      s2 = fmaf(v4.y, v4.y, s2);
      s2 = fmaf(v4.z, v4.z, s2);
      s2 = fmaf(v4.w, v4.w, s2);
    }
    s1 += __shfl_xor(s1, 16, 64); s2 += __shfl_xor(s2, 16, 64);
    s1 += __shfl_xor(s1, 32, 64); s2 += __shfl_xor(s2, 32, 64);
    if (lane < 16) { red[jj][wv * 2] = s1; red[jj][wv * 2 + 1] = s2; }
  }
  __syncthreads();

  // per-j stats computed ONCE by 16 threads
  if (a < KNN) {
    const float4 rr = *(const float4*)red[a];
    float S1 = rr.x + rr.z;
    float S2 = rr.y + rr.w;
    float mu  = S1 * (1.f / AD);
    float var = fmaf(S2, 1.f / AD, -mu * mu);
    statS[a][0] = mu;
    statS[a][1] = rsqrtf(var + EPSV);
  }
  __syncthreads();

  // LN apply + softmax (no max pass: |s| <= 1.45 in exp2 domain, shift-inv.)
  float sum = 0.f;
  #pragma unroll
  for (int j = 0; j < KNN; ++j) {
    const float2 st = *(const float2*)statS[j];
    float s = fmaf((x[j] - st.x) * st.y, gr, brv);
    float p = exp2f(s);
    x[j] = p;
    sum += p;
  }
  const float inv = 1.f / sum;
  float o = 0.f;
  #pragma unroll
  for (int j = 0; j < KNN; ++j)
    o = fmaf(x[j], w[j], o);
  out[(size_t)n * 256 + (gbr ? 128 : 0) + a] = o * inv;
}

// ---------------- proj MLP via MFMA hi/lo: grid 1250 x 256 ------------------
__global__ void proj_mfma(const float* __restrict__ attn_cat,
                          const unsigned short* __restrict__ w1f, const float* __restrict__ b1,
                          const unsigned short* __restrict__ w2f, const float* __restrict__ b2,
                          float* __restrict__ outp)
{
  __shared__ __align__(16) unsigned short aHi[16 * 256];
  __shared__ __align__(16) unsigned short aLo[16 * 256];
  const int tid  = threadIdx.x;
  const int lane = tid & 63;
  const int wv   = tid >> 6;
  const int row0 = blockIdx.x * 16;

  {
    int r = tid >> 4, seg = tid & 15;
    const float4* src = (const float4*)(attn_cat + (size_t)(row0 + r) * 256 + seg * 16);
    #pragma unroll
    for (int q4 = 0; q4 < 4; ++q4) {
      float4 f = src[q4];
      int byte = (r * 512 + (seg * 16 + q4 * 4) * 2) ^ ((r & 7) << 4);
      ushort4 h, l2;
      h.x = f2b(f.x); l2.x = f2b(f.x - b2f(h.x));
      h.y = f2b(f.y); l2.y = f2b(f.y - b2f(h.y));
      h.z = f2b(f.z); l2.z = f2b(f.z - b2f(h.z));
      h.w = f2b(f.w); l2.w = f2b(f.w - b2f(h.w));
      *(ushort4*)((char*)aHi + byte) = h;
      *(ushort4*)((char*)aLo + byte) = l2;
    }
  }
  __syncthreads();

  short8v ah[8], al[8];
  #pragma unroll
  for (int ks = 0; ks < 8; ++ks) {
    int base = ((lane & 15) * 512 + ks * 64 + (lane >> 4) * 16) ^ ((lane & 7) << 4);
    ah[ks] = *(const short8v*)((const char*)aHi + base);
    al[ks] = *(const short8v*)((const char*)aLo + base);
  }
  __syncthreads();

  const short8v* w1H = (const short8v*)w1f;
  const short8v* w1L = w1H + 8192;
  f32x4 acc[4];
  #pragma unroll
  for (int t = 0; t < 4; ++t) acc[t] = (f32x4){0.f, 0.f, 0.f, 0.f};
  #pragma unroll
  for (int t = 0; t < 4; ++t) {
    int tt = wv * 4 + t;
    #pragma unroll
    for (int ks = 0; ks < 8; ++ks) {
      short8v bh = w1H[(tt * 8 + ks) * 64 + lane];
      short8v bo = w1L[(tt * 8 + ks) * 64 + lane];
      acc[t] = __builtin_amdgcn_mfma_f32_16x16x32_bf16(ah[ks], bh, acc[t], 0, 0, 0);
      acc[t] = __builtin_amdgcn_mfma_f32_16x16x32_bf16(al[ks], bh, acc[t], 0, 0, 0);
      acc[t] = __builtin_amdgcn_mfma_f32_16x16x32_bf16(ah[ks], bo, acc[t], 0, 0, 0);
    }
  }
  #pragma unroll
  for (int t = 0; t < 4; ++t) {
    int col = (wv * 4 + t) * 16 + (lane & 15);
    float bvv = b1[col];
    #pragma unroll
    for (int r = 0; r < 4; ++r) {
      int row = (lane >> 4) * 4 + r;
      float h = fmaxf(acc[t][r] + bvv, 0.f);
      unsigned short hi = f2b(h);
      unsigned short lo = f2b(h - b2f(hi));
      int byte = (row * 512 + col * 2) ^ ((row & 7) << 4);
      *(unsigned short*)((char*)aHi + byte) = hi;
      *(unsigned short*)((char*)aLo + byte) = lo;
    }
  }
  __syncthreads();

  #pragma unroll
  for (int ks = 0; ks < 8; ++ks) {
    int base = ((lane & 15) * 512 + ks * 64 + (lane >> 4) * 16) ^ ((lane & 7) << 4);
    ah[ks] = *(const short8v*)((const char*)aHi + base);
    al[ks] = *(const short8v*)((const char*)aLo + base);
  }
  const short8v* w2H = (const short8v*)w2f;
  const short8v* w2L = w2H + 8192;
  #pragma unroll
  for (int t = 0; t < 4; ++t) acc[t] = (f32x4){0.f, 0.f, 0.f, 0.f};
  #pragma unroll
  for (int t = 0; t < 4; ++t) {
    int tt = wv * 4 + t;
    #pragma unroll
    for (int ks = 0; ks < 8; ++ks) {
      short8v bh = w2H[(tt * 8 + ks) * 64 + lane];
      short8v bo = w2L[(tt * 8 + ks) * 64 + lane];
      acc[t] = __builtin_amdgcn_mfma_f32_16x16x32_bf16(ah[ks], bh, acc[t], 0, 0, 0);
      acc[t] = __builtin_amdgcn_mfma_f32_16x16x32_bf16(al[ks], bh, acc[t], 0, 0, 0);
      acc[t] = __builtin_amdgcn_mfma_f32_16x16x32_bf16(ah[ks], bo, acc[t], 0, 0, 0);
    }
  }
  #pragma unroll
  for (int t = 0; t < 4; ++t) {
    int col = (wv * 4 + t) * 16 + (lane & 15);
    float bvv = b2[col];
    #pragma unroll
    for (int r = 0; r < 4; ++r) {
      int row = (lane >> 4) * 4 + r;
      outp[(size_t)(row0 + row) * 256 + col] = acc[t][r] + bvv;
    }
  }
}

// ---------------- launch ----------------------------------------------------
extern "C" void kernel_launch(void* const* d_in, const int* in_sizes, int n_in,
                              void* d_out, int out_size, void* d_ws, size_t ws_size,
                              hipStream_t stream)
{
  const float* events   = (const float*)d_in[0];
  const float* features = (const float*)d_in[1];
  const int* local_idx    = (const int*)d_in[2];
  const int* down_idx     = (const int*)d_in[3];
  const int* pair_idx     = (const int*)d_in[4];
  const int* inv_pair_idx = (const int*)d_in[5];
  const float* l_qkv_w = (const float*)d_in[6];
  const float* l_qkv_b = (const float*)d_in[7];
  const float* l_pe_w1 = (const float*)d_in[8];
  const float* l_pe_b1 = (const float*)d_in[9];
  const float* l_pe_w2 = (const float*)d_in[10];
  const float* l_pe_b2 = (const float*)d_in[11];
  const float* l_fc_g  = (const float*)d_in[12];
  const float* l_fc_b  = (const float*)d_in[13];
  const float* g_qkv_w = (const float*)d_in[14];
  const float* g_qkv_b = (const float*)d_in[15];
  const float* g_pe_w1 = (const float*)d_in[16];
  const float* g_pe_b1 = (const float*)d_in[17];
  const float* g_pe_w2 = (const float*)d_in[18];
  const float* g_pe_b2 = (const float*)d_in[19];
  const float* g_fc_g  = (const float*)d_in[20];
  const float* g_fc_b  = (const float*)d_in[21];
  const float* p_w1 = (const float*)d_in[22];
  const float* p_b1 = (const float*)d_in[23];
  const float* p_w2 = (const float*)d_in[24];
  const float* p_b2 = (const float*)d_in[25];
  (void)in_sizes; (void)n_in; (void)out_size; (void)ws_size;

  char* ws = (char*)d_ws;
  size_t off = 0;
  float* qkv_l    = (float*)(ws + off); off += (size_t)N_PTS * 384 * 4;
  float* qkv_g    = (float*)(ws + off); off += (size_t)N_PTS * 384 * 4;
  unsigned short* kvl = (unsigned short*)(ws + off); off += (size_t)N_PTS * 256 * 2;
  unsigned int*   kvm = (unsigned int*)(ws + off);   off += (size_t)MD * AD * 4;
  float* attn_cat = (float*)(ws + off); off += (size_t)N_PTS * 256 * 4;
  unsigned short* w2B   = (unsigned short*)(ws + off); off += 32768 * 2;
  unsigned short* wfL   = (unsigned short*)(ws + off); off += 196608 * 2;
  unsigned short* wfG   = (unsigned short*)(ws + off); off += 196608 * 2;
  unsigned short* wp1   = (unsigned short*)(ws + off); off += 131072 * 2;
  unsigned short* wp2   = (unsigned short*)(ws + off); off += 131072 * 2;

  EventAttention_54382875902362_kernel<<<1, 64, 0, stream>>>((float*)d_out);
  prep_all<<<1408, 256, 0, stream>>>(
      l_pe_w2, g_pe_w2, l_qkv_w, g_qkv_w, p_w1, p_w2,
      w2B, wfL, wfG, wp1, wp2);

  qkv_mfma<<<2500, 256, 0, stream>>>(
      features, wfL, l_qkv_b, wfG, g_qkv_b, qkv_l, qkv_g, kvl);
  kvmax_kernel<<<MD, 128, 0, stream>>>(qkv_g, pair_idx, kvm);
  attn_fused<<<2 * N_PTS, 128, 0, stream>>>(
      events, local_idx, inv_pair_idx, down_idx,
      qkv_l, qkv_g, (const unsigned int*)kvl, kvm,
      l_pe_w1, l_pe_b1, w2B, l_pe_b2, l_fc_g, l_fc_b,
      g_pe_w1, g_pe_b1, w2B + 16384, g_pe_b2, g_fc_g, g_fc_b,
      attn_cat);
  proj_mfma<<<N_PTS / 16, 256, 0, stream>>>(
      attn_cat, wp1, p_b1, wp2, p_b2, (float*)d_out);
}